// Round 1
// baseline (502.440 us; speedup 1.0000x reference)
//
#include <hip/hip_runtime.h>

typedef __bf16 bf16;
typedef bf16 bf16x8 __attribute__((ext_vector_type(8)));
typedef bf16 bf16x4 __attribute__((ext_vector_type(4)));
typedef float f32x4 __attribute__((ext_vector_type(4)));

#define DEV static __device__ __forceinline__

DEV bf16 f2bf(float f) {
  unsigned u = __builtin_bit_cast(unsigned, f);
  u += 0x7fffu + ((u >> 16) & 1u);               // RNE
  unsigned short h = (unsigned short)(u >> 16);
  return __builtin_bit_cast(bf16, h);
}
DEV float bf2f(bf16 b) {
  unsigned short h = __builtin_bit_cast(unsigned short, b);
  unsigned u = ((unsigned)h) << 16;
  return __builtin_bit_cast(float, u);
}

// ---------------------------------------------------------------------------
// Prologue A: convert+transpose weights to bf16 [N][K]; also wb = Wo@bo, c=||bo||^2
// grid 329 x 256
// ---------------------------------------------------------------------------
__global__ void kTrans(const float* __restrict__ Wq, const float* __restrict__ Wk,
                       const float* __restrict__ Wv, const float* __restrict__ Wo,
                       const float* __restrict__ bo,
                       bf16* __restrict__ WqT, bf16* __restrict__ WkT,
                       bf16* __restrict__ WvT, bf16* __restrict__ WoT,
                       float* __restrict__ wb, float* __restrict__ cbuf)
{
  __shared__ float tl[32][33];
  __shared__ float r2[4];
  const int id = blockIdx.x;
  const int t = threadIdx.x;
  if (id < 320) {
    const float* src; bf16* dst; int R, C, t2;
    if (id < 64)       { src = Wq; dst = WqT; R = 512; C = 128; t2 = id; }
    else if (id < 160) { src = Wk; dst = WkT; R = 768; C = 128; t2 = id - 64; }
    else if (id < 256) { src = Wv; dst = WvT; R = 768; C = 128; t2 = id - 160; }
    else               { src = Wo; dst = WoT; R = 128; C = 512; t2 = id - 256; }
    const int tcn = C >> 5;
    const int tc = t2 % tcn, tr = t2 / tcn;
    const int tx = t & 31, ty = t >> 5;   // 32 x 8
    #pragma unroll
    for (int k = 0; k < 4; ++k)
      tl[ty + 8 * k][tx] = src[(size_t)(tr * 32 + ty + 8 * k) * C + tc * 32 + tx];
    __syncthreads();
    #pragma unroll
    for (int k = 0; k < 4; ++k)
      dst[(size_t)(tc * 32 + ty + 8 * k) * R + tr * 32 + tx] = f2bf(tl[tx][ty + 8 * k]);
  } else if (id < 328) {
    // wb[d] = sum_n Wo[d][n]*bo[n] ; 16 rows per block
    const int b = id - 320;
    const int d = b * 16 + (t >> 4);
    const int seg = t & 15;
    float p = 0.f;
    #pragma unroll 4
    for (int n = 0; n < 32; ++n) p += Wo[(size_t)d * 512 + seg * 32 + n] * bo[seg * 32 + n];
    p += __shfl_xor(p, 1); p += __shfl_xor(p, 2); p += __shfl_xor(p, 4); p += __shfl_xor(p, 8);
    if (seg == 0) wb[d] = p;
  } else {
    float p = 0.f;
    for (int n = t; n < 512; n += 256) { float b_ = bo[n]; p += b_ * b_; }
    p += __shfl_xor(p, 1); p += __shfl_xor(p, 2); p += __shfl_xor(p, 4);
    p += __shfl_xor(p, 8); p += __shfl_xor(p, 16); p += __shfl_xor(p, 32);
    if ((t & 63) == 0) r2[t >> 6] = p;
    __syncthreads();
    if (t == 0) cbuf[0] = r2[0] + r2[1] + r2[2] + r2[3];
  }
}

// ---------------------------------------------------------------------------
// Prologue B: G = Wo @ Wo^T  (128x128 bf16), tiled 32x32. grid 16 x 256
// ---------------------------------------------------------------------------
__global__ __launch_bounds__(256) void kG(const float* __restrict__ Wo, bf16* __restrict__ G)
{
  __shared__ float Abuf[32][68];
  __shared__ float Bbuf[32][68];
  const int t = threadIdx.x;
  const int ti = blockIdx.x >> 2, tj = blockIdx.x & 3;
  const int i = t >> 3;           // 0..31
  const int j4 = (t & 7) * 4;     // 0,4,...,28
  const int q = t & 15, rr = t >> 4;
  float acc[4] = {0.f, 0.f, 0.f, 0.f};
  for (int k0 = 0; k0 < 512; k0 += 64) {
    __syncthreads();
    #pragma unroll
    for (int h = 0; h < 2; ++h) {
      int r = rr + 16 * h;
      *(float4*)&Abuf[r][q * 4] = *(const float4*)(Wo + (size_t)(ti * 32 + r) * 512 + k0 + q * 4);
      *(float4*)&Bbuf[r][q * 4] = *(const float4*)(Wo + (size_t)(tj * 32 + r) * 512 + k0 + q * 4);
    }
    __syncthreads();
    #pragma unroll 8
    for (int n = 0; n < 64; ++n) {
      float a = Abuf[i][n];
      #pragma unroll
      for (int jj = 0; jj < 4; ++jj) acc[jj] += a * Bbuf[j4 + jj][n];
    }
  }
  #pragma unroll
  for (int jj = 0; jj < 4; ++jj)
    G[(size_t)(ti * 32 + i) * 128 + tj * 32 + j4 + jj] = f2bf(acc[jj]);
}

// ---------------------------------------------------------------------------
// Kernel 1: fused qkv projections + softmax/sigmoid + linear attention + norm
// grid 512 x 512 threads (8 waves, 2x4 over the 128x128 tile)
// ---------------------------------------------------------------------------
__global__ __launch_bounds__(512) void k1_attn(
    const float* __restrict__ x, const float* __restrict__ ctx,
    const bf16* __restrict__ WqT, const bf16* __restrict__ WkT,
    const bf16* __restrict__ WvT, const bf16* __restrict__ G,
    const float* __restrict__ wb, const float* __restrict__ cbuf,
    bf16* __restrict__ att, float* __restrict__ invw)
{
  __shared__ __align__(16) bf16 As[128][72];
  __shared__ __align__(16) bf16 Bs[2][128][72];
  __shared__ float wbs[128];
  __shared__ float rowsum[128][4];
  __shared__ float invs[128];

  const int tid  = threadIdx.x;
  const int lane = tid & 63;
  const int wave = tid >> 6;
  const int wr   = (wave >> 2) * 64;   // wave row base
  const int wc   = (wave & 3) * 32;    // wave col base (one head per wave)
  const int l15  = lane & 15;
  const int lg   = lane >> 4;
  const int r0   = blockIdx.x * 128;

  const int sq   = tid & 15;  // A staging: col quad
  const int srow = tid >> 4;  // A staging: row base 0..31
  const int so   = tid & 7;   // B staging: col oct
  const int sbr  = tid >> 3;  // B staging: row base 0..63

  if (tid < 128) wbs[tid] = wb[tid];

  f32x4 kacc[4][2] = {};
  f32x4 vacc[4][2] = {};

  // ---------------- fused K/V pass over ctx (K = 768) ----------------
  for (int k0 = 0; k0 < 768; k0 += 64) {
    __syncthreads();
    #pragma unroll
    for (int i = 0; i < 4; ++i) {
      int r = srow + 32 * i;
      const float4 v4 = *(const float4*)(ctx + (size_t)(r0 + r) * 768 + k0 + sq * 4);
      bf16x4 tt; tt[0] = f2bf(v4.x); tt[1] = f2bf(v4.y); tt[2] = f2bf(v4.z); tt[3] = f2bf(v4.w);
      *(bf16x4*)(&As[r][sq * 4]) = tt;
    }
    #pragma unroll
    for (int i = 0; i < 2; ++i) {
      int n = sbr + 64 * i;
      *(bf16x8*)(&Bs[0][n][so * 8]) = *(const bf16x8*)(WkT + (size_t)n * 768 + k0 + so * 8);
      *(bf16x8*)(&Bs[1][n][so * 8]) = *(const bf16x8*)(WvT + (size_t)n * 768 + k0 + so * 8);
    }
    __syncthreads();
    #pragma unroll
    for (int ks = 0; ks < 2; ++ks) {
      bf16x8 af[4], bk[2], bv[2];
      #pragma unroll
      for (int tm = 0; tm < 4; ++tm)
        af[tm] = *(const bf16x8*)(&As[wr + tm * 16 + l15][ks * 32 + lg * 8]);
      #pragma unroll
      for (int tn = 0; tn < 2; ++tn) {
        bk[tn] = *(const bf16x8*)(&Bs[0][wc + tn * 16 + l15][ks * 32 + lg * 8]);
        bv[tn] = *(const bf16x8*)(&Bs[1][wc + tn * 16 + l15][ks * 32 + lg * 8]);
      }
      #pragma unroll
      for (int tm = 0; tm < 4; ++tm)
        #pragma unroll
        for (int tn = 0; tn < 2; ++tn) {
          kacc[tm][tn] = __builtin_amdgcn_mfma_f32_16x16x32_bf16(af[tm], bk[tn], kacc[tm][tn], 0, 0, 0);
          vacc[tm][tn] = __builtin_amdgcn_mfma_f32_16x16x32_bf16(af[tm], bv[tn], vacc[tm][tn], 0, 0, 0);
        }
    }
  }

  // ---------------- Q pass over x (K = 512) ----------------
  f32x4 qacc[4][2] = {};
  for (int k0 = 0; k0 < 512; k0 += 64) {
    __syncthreads();
    #pragma unroll
    for (int i = 0; i < 4; ++i) {
      int r = srow + 32 * i;
      const float4 v4 = *(const float4*)(x + (size_t)(r0 + r) * 512 + k0 + sq * 4);
      bf16x4 tt; tt[0] = f2bf(v4.x); tt[1] = f2bf(v4.y); tt[2] = f2bf(v4.z); tt[3] = f2bf(v4.w);
      *(bf16x4*)(&As[r][sq * 4]) = tt;
    }
    #pragma unroll
    for (int i = 0; i < 2; ++i) {
      int n = sbr + 64 * i;
      *(bf16x8*)(&Bs[0][n][so * 8]) = *(const bf16x8*)(WqT + (size_t)n * 512 + k0 + so * 8);
    }
    __syncthreads();
    #pragma unroll
    for (int ks = 0; ks < 2; ++ks) {
      bf16x8 af[4], bq[2];
      #pragma unroll
      for (int tm = 0; tm < 4; ++tm)
        af[tm] = *(const bf16x8*)(&As[wr + tm * 16 + l15][ks * 32 + lg * 8]);
      #pragma unroll
      for (int tn = 0; tn < 2; ++tn)
        bq[tn] = *(const bf16x8*)(&Bs[0][wc + tn * 16 + l15][ks * 32 + lg * 8]);
      #pragma unroll
      for (int tm = 0; tm < 4; ++tm)
        #pragma unroll
        for (int tn = 0; tn < 2; ++tn)
          qacc[tm][tn] = __builtin_amdgcn_mfma_f32_16x16x32_bf16(af[tm], bq[tn], qacc[tm][tn], 0, 0, 0);
    }
  }

  // ---------------- softmax(q)*scale, sigmoid(k), s = <q,k> per (row,head) ----
  // wave's 32 cols = exactly one head; a head's cols live in one 16-lane group
  // (lane&15) x 2 n-tiles -> xor-shuffle reductions over masks 1,2,4,8.
  const float scale = 0.17677669529663687f;  // 32^-0.5
  float sreg[4][4];
  #pragma unroll
  for (int tm = 0; tm < 4; ++tm) {
    #pragma unroll
    for (int r = 0; r < 4; ++r) {
      float q0 = qacc[tm][0][r], q1 = qacc[tm][1][r];
      float m = fmaxf(q0, q1);
      m = fmaxf(m, __shfl_xor(m, 1));
      m = fmaxf(m, __shfl_xor(m, 2));
      m = fmaxf(m, __shfl_xor(m, 4));
      m = fmaxf(m, __shfl_xor(m, 8));
      float e0 = __expf(q0 - m), e1 = __expf(q1 - m);
      float es = e0 + e1;
      es += __shfl_xor(es, 1);
      es += __shfl_xor(es, 2);
      es += __shfl_xor(es, 4);
      es += __shfl_xor(es, 8);
      float rs = scale / es;
      float kk0 = 1.f / (1.f + __expf(-kacc[tm][0][r]));
      float kk1 = 1.f / (1.f + __expf(-kacc[tm][1][r]));
      float sp = e0 * rs * kk0 + e1 * rs * kk1;
      sp += __shfl_xor(sp, 1);
      sp += __shfl_xor(sp, 2);
      sp += __shfl_xor(sp, 4);
      sp += __shfl_xor(sp, 8);
      sreg[tm][r] = sp;
    }
  }

  // ---------------- out = s*v -> regs + LDS (outs = As cols 0..63 | Bs[0] cols 64..127)
  __syncthreads();
  #pragma unroll
  for (int tm = 0; tm < 4; ++tm)
    #pragma unroll
    for (int tn = 0; tn < 2; ++tn)
      #pragma unroll
      for (int r = 0; r < 4; ++r) {
        float ov = sreg[tm][r] * vacc[tm][tn][r];
        vacc[tm][tn][r] = ov;
        int row = wr + tm * 16 + lg * 4 + r;
        int col = wc + tn * 16 + l15;
        bf16 bv_ = f2bf(ov);
        if (col < 64) As[row][col] = bv_;
        else          Bs[0][row][col - 64] = bv_;
      }
  __syncthreads();

  // ---------------- quad form t = out @ G ; ssq = out.(t + 2 wb) + c ----------
  f32x4 tacc[4][2] = {};
  #pragma unroll
  for (int ks = 0; ks < 4; ++ks) {
    bf16x8 af[4], bg[2];
    const int kk = ks * 32 + lg * 8;
    #pragma unroll
    for (int tm = 0; tm < 4; ++tm) {
      int row = wr + tm * 16 + l15;
      af[tm] = *(const bf16x8*)((kk < 64) ? &As[row][kk] : &Bs[0][row][kk - 64]);
    }
    #pragma unroll
    for (int tn = 0; tn < 2; ++tn) {
      int n = wc + tn * 16 + l15;
      bg[tn] = *(const bf16x8*)(G + (size_t)n * 128 + kk);
    }
    #pragma unroll
    for (int tm = 0; tm < 4; ++tm)
      #pragma unroll
      for (int tn = 0; tn < 2; ++tn)
        tacc[tm][tn] = __builtin_amdgcn_mfma_f32_16x16x32_bf16(af[tm], bg[tn], tacc[tm][tn], 0, 0, 0);
  }
  #pragma unroll
  for (int tm = 0; tm < 4; ++tm)
    #pragma unroll
    for (int r = 0; r < 4; ++r) {
      float p = 0.f;
      #pragma unroll
      for (int tn = 0; tn < 2; ++tn) {
        int col = wc + tn * 16 + l15;
        p += vacc[tm][tn][r] * (tacc[tm][tn][r] + 2.f * wbs[col]);
      }
      p += __shfl_xor(p, 1);
      p += __shfl_xor(p, 2);
      p += __shfl_xor(p, 4);
      p += __shfl_xor(p, 8);
      if (l15 == 0) rowsum[wr + tm * 16 + lg * 4 + r][wave & 3] = p;
    }
  __syncthreads();
  if (tid < 128) {
    float ssq = rowsum[tid][0] + rowsum[tid][1] + rowsum[tid][2] + rowsum[tid][3] + cbuf[0];
    float nrm = sqrtf(fmaxf(ssq, 0.f));
    float iv = 22.627416997969522f / fmaxf(nrm, 1e-12f);  // sqrt(512)/max(||y||,eps)
    invs[tid] = iv;
    invw[r0 + tid] = iv;
  }
  __syncthreads();

  // ---------------- att = out * inv (coalesced 16B stores) ----------------
  const int oc = tid & 15;
  const int orw = tid >> 4;  // 0..31
  #pragma unroll
  for (int i = 0; i < 4; ++i) {
    int row = orw + 32 * i;
    const bf16* src = (oc < 8) ? &As[row][oc * 8] : &Bs[0][row][(oc - 8) * 8];
    bf16x8 vv = *(const bf16x8*)src;
    float ivr = invs[row];
    bf16x8 ov;
    #pragma unroll
    for (int j = 0; j < 8; ++j) ov[j] = f2bf(bf2f(vv[j]) * ivr);
    *(bf16x8*)(att + (size_t)(r0 + row) * 128 + oc * 8) = ov;
  }
}

// ---------------------------------------------------------------------------
// Kernel 2: y = out_s @ Wo, epilogue (+bo*inv)*g.  grid 512 x 256
// ---------------------------------------------------------------------------
__global__ __launch_bounds__(256) void k2_proj(
    const bf16* __restrict__ att, const bf16* __restrict__ WoT,
    const float* __restrict__ invw, const float* __restrict__ bo,
    const float* __restrict__ g, float* __restrict__ out)
{
  __shared__ __align__(16) bf16 As2[128][136];
  __shared__ __align__(16) bf16 Bs2[128][72];
  __shared__ float gs[512], bos[512], iv2[128];

  const int tid = threadIdx.x;
  const int lane = tid & 63, wave = tid >> 6;
  const int wr = (wave >> 1) * 64, wc = (wave & 1) * 64;
  const int l15 = lane & 15, lg = lane >> 4;
  const int r0 = blockIdx.x * 128;

  // stage A tile (full K=128) + small vectors
  {
    const int oc = tid & 15, rb = tid >> 4;
    #pragma unroll
    for (int i = 0; i < 8; ++i) {
      int row = rb + 16 * i;
      *(bf16x8*)(&As2[row][oc * 8]) = *(const bf16x8*)(att + (size_t)(r0 + row) * 128 + oc * 8);
    }
    gs[tid] = g[tid];  gs[tid + 256] = g[tid + 256];
    bos[tid] = bo[tid]; bos[tid + 256] = bo[tid + 256];
    if (tid < 128) iv2[tid] = invw[r0 + tid];
  }

  const int so = tid & 7, sbr = tid >> 3;  // B staging
  for (int nc = 0; nc < 4; ++nc) {
    f32x4 acc[4][4] = {};
    for (int kh = 0; kh < 2; ++kh) {
      __syncthreads();
      #pragma unroll
      for (int i = 0; i < 2; ++i) {
        int row = sbr + 32 * i;  // wait: sbr 0..31 -> rows 0..63? fixed below
        (void)row;
      }
      // stage Bs2 = WoT[nc*128 + n][kh*64 .. +64] : 128 x 64 bf16
      #pragma unroll
      for (int i = 0; i < 4; ++i) {
        int n = (tid >> 3) + 32 * i;  // 0..127
        *(bf16x8*)(&Bs2[n][so * 8]) =
            *(const bf16x8*)(WoT + (size_t)(nc * 128 + n) * 128 + kh * 64 + so * 8);
      }
      __syncthreads();
      #pragma unroll
      for (int ks = 0; ks < 2; ++ks) {
        bf16x8 af[4], bfr[4];
        #pragma unroll
        for (int tm = 0; tm < 4; ++tm)
          af[tm] = *(const bf16x8*)(&As2[wr + tm * 16 + l15][kh * 64 + ks * 32 + lg * 8]);
        #pragma unroll
        for (int tn = 0; tn < 4; ++tn)
          bfr[tn] = *(const bf16x8*)(&Bs2[wc + tn * 16 + l15][ks * 32 + lg * 8]);
        #pragma unroll
        for (int tm = 0; tm < 4; ++tm)
          #pragma unroll
          for (int tn = 0; tn < 4; ++tn)
            acc[tm][tn] = __builtin_amdgcn_mfma_f32_16x16x32_bf16(af[tm], bfr[tn], acc[tm][tn], 0, 0, 0);
      }
    }
    #pragma unroll
    for (int tm = 0; tm < 4; ++tm)
      #pragma unroll
      for (int tn = 0; tn < 4; ++tn)
        #pragma unroll
        for (int r = 0; r < 4; ++r) {
          int row = wr + tm * 16 + lg * 4 + r;
          int col = nc * 128 + wc + tn * 16 + l15;
          float v = acc[tm][tn][r] + bos[col] * iv2[row];
          v *= gs[col];
          out[(size_t)(r0 + row) * 512 + col] = v;
        }
  }
}

// ---------------------------------------------------------------------------
extern "C" void kernel_launch(void* const* d_in, const int* in_sizes, int n_in,
                              void* d_out, int out_size, void* d_ws, size_t ws_size,
                              hipStream_t stream)
{
  (void)in_sizes; (void)n_in; (void)out_size; (void)ws_size;
  const float* x   = (const float*)d_in[0];
  const float* ctx = (const float*)d_in[1];
  const float* Wq  = (const float*)d_in[2];
  const float* Wk  = (const float*)d_in[3];
  const float* Wv  = (const float*)d_in[4];
  const float* Wo  = (const float*)d_in[5];
  const float* bo  = (const float*)d_in[6];
  const float* g   = (const float*)d_in[7];
  float* out = (float*)d_out;

  char* w = (char*)d_ws;
  bf16*  WqT = (bf16*)(w + 0);          // 128*512*2  = 131072
  bf16*  WkT = (bf16*)(w + 131072);     // 128*768*2  = 196608
  bf16*  WvT = (bf16*)(w + 327680);     // 196608
  bf16*  WoT = (bf16*)(w + 524288);     // 512*128*2  = 131072
  bf16*  G   = (bf16*)(w + 655360);     // 128*128*2  = 32768
  float* wb  = (float*)(w + 688128);    // 512
  float* cb  = (float*)(w + 688640);    // 64
  bf16*  att = (bf16*)(w + 689152);     // 65536*128*2 = 16777216
  float* inv = (float*)(w + 689152 + 16777216);  // 65536*4 = 262144

  kTrans<<<dim3(329), dim3(256), 0, stream>>>(Wq, Wk, Wv, Wo, bo, WqT, WkT, WvT, WoT, wb, cb);
  kG<<<dim3(16), dim3(256), 0, stream>>>(Wo, G);
  k1_attn<<<dim3(512), dim3(512), 0, stream>>>(x, ctx, WqT, WkT, WvT, G, wb, cb, att, inv);
  k2_proj<<<dim3(512), dim3(256), 0, stream>>>(att, WoT, inv, bo, g, out);
}